// Round 13
// baseline (1600.134 us; speedup 1.0000x reference)
//
#include <hip/hip_runtime.h>
#include <stdint.h>

typedef _Float16 f16;
typedef _Float16 f16x8 __attribute__((ext_vector_type(8)));
typedef float f32x4 __attribute__((ext_vector_type(4)));

#define INF_F __builtin_inff()
#define INF_I 0x7fffffff
#define KM 24            // merge candidate margin
#define SCALE 262144.0f  // 2^18 fixed-point scale

__device__ __forceinline__ bool lexLess(float s1, int n1, float s2, int n2) {
    return (s1 < s2) || (s1 == s2 && n1 < n2);
}
__device__ __forceinline__ bool lexLessI(int s1, int n1, int s2, int n2) {
    return (s1 < s2) || (s1 == s2 && n1 < n2);
}

__device__ __forceinline__ uint4 pack8(const float4 a, const float4 b) {
    const auto p0 = __builtin_amdgcn_cvt_pkrtz(a.x, a.y);
    const auto p1 = __builtin_amdgcn_cvt_pkrtz(a.z, a.w);
    const auto p2 = __builtin_amdgcn_cvt_pkrtz(b.x, b.y);
    const auto p3 = __builtin_amdgcn_cvt_pkrtz(b.z, b.w);
    uint4 u;
    u.x = __builtin_bit_cast(unsigned, p0);
    u.y = __builtin_bit_cast(unsigned, p1);
    u.z = __builtin_bit_cast(unsigned, p2);
    u.w = __builtin_bit_cast(unsigned, p3);
    return u;
}
__device__ __forceinline__ uint2 pack4(const float4 a) {
    const auto p0 = __builtin_amdgcn_cvt_pkrtz(a.x, a.y);
    const auto p1 = __builtin_amdgcn_cvt_pkrtz(a.z, a.w);
    uint2 u;
    u.x = __builtin_bit_cast(unsigned, p0);
    u.y = __builtin_bit_cast(unsigned, p1);
    return u;
}
__device__ __forceinline__ float ssum(const float4 v) {
    return fmaf(v.x, v.x, fmaf(v.y, v.y, fmaf(v.z, v.z, v.w * v.w)));
}

#define YROWB 1040   // LDS bytes per staged f16 row (512*2 + 16 pad)

// ---------------------------------------------------------------------------
// Kernel 1: contiguous-stream scores + per-block top-16 per batch row.
// 8 waves (512 threads); tile = 16 rep rows (32 KB contiguous per block).
// Stage: wave w loads its 2 rows (4 KB SEQUENTIAL, 4x 1KB wave-coalesced
// loads) -> regs early; cvt+ds_write late (latency hides under compute).
// Compute: wave w owns k-slice [64w,64w+64), A in 32 VGPRs; B-frags via
// ds_read from the f16 LDS tile. Exact int32 fold (LDS atomics) into
// double-buffered slds. ynorm: f32 shfl tree -> ynI TRIPLE-buffered
// (lifetime write@sc -> read@sc+2 spans 3 phases; double-buffer raced: R12).
// ONE raw s_barrier + lgkmcnt(0) per tile (vmcnt stays counted across it).
// Rotating wave scans tile t-1 (16 iters) overlapped with tile t.
// ---------------------------------------------------------------------------
__global__ __launch_bounds__(512, 4) void dist_topk_kernel(
    const float* __restrict__ reps, const float* __restrict__ brep,
    float* __restrict__ cs, int* __restrict__ ci,
    int N, int TT, int NBLK)
{
    __shared__ __align__(16) char ybuf[2][16 * YROWB];   // 33.3 KB f16 tiles
    __shared__ int slds[2][16][65];                      // 8.3 KB int dots
    __shared__ int ynI[3][16];                           // TRIPLE-buffered norms
    __shared__ int topdI[16][64];
    __shared__ int topiI[16][64];
    __shared__ int thrS[64], thrnS[64], cntS[64];

    const int tid = threadIdx.x;
    const int w = tid >> 6, lane = tid & 63;
    const int li = lane & 15, q = lane >> 4;
    const int b = blockIdx.x;

    // ---- A-fragments for this wave's k-slice (32 VGPR), from L2-hot brep ----
    uint4 a[2][4];
    #pragma unroll
    for (int ks2 = 0; ks2 < 2; ks2++)
        #pragma unroll
        for (int mt = 0; mt < 4; mt++) {
            const float* src = brep + (mt * 16 + li) * 512 + 64 * w + 32 * ks2 + 8 * q;
            a[ks2][mt] = pack8(*(const float4*)(src), *(const float4*)(src + 4));
        }

    if (tid < 64) { thrS[tid] = INF_I; thrnS[tid] = INF_I; cntS[tid] = 0; }
    for (int i = tid; i < 2 * 16 * 65; i += 512) ((int*)slds)[i] = 0;

    const int myCnt = (TT - b + NBLK - 1) / NBLK;   // tiles for this block

    float4 st[4];
    // issue loads of tile t into st: piece i = row (2w + (i>>1)), half (i&1)
    auto issue = [&](int t) {
        const int r0 = t * 16 + 2 * w;
        #pragma unroll
        for (int i = 0; i < 4; i++) {
            int rr = r0 + (i >> 1); if (rr >= N) rr = N - 1;
            st[i] = *(const float4*)((const char*)(reps + (size_t)rr * 512)
                                     + (i & 1) * 1024 + lane * 16);
        }
    };
    // cvt st -> f16 LDS tile ybuf[yb], + ynorm into ynI[yi] (single writer)
    auto cvt_write = [&](int yb, int yi) {
        char* base = ybuf[yb];
        #pragma unroll
        for (int i = 0; i < 4; i++) {
            const uint2 u = pack4(st[i]);
            *(uint2*)(base + (2 * w + (i >> 1)) * YROWB
                      + ((i & 1) * 256 + lane * 4) * 2) = u;
        }
        float s0 = ssum(st[0]) + ssum(st[1]);
        float s1 = ssum(st[2]) + ssum(st[3]);
        #pragma unroll
        for (int d = 1; d < 64; d <<= 1) {
            s0 += __shfl_xor(s0, d);
            s1 += __shfl_xor(s1, d);
        }
        if (lane == 0) {
            ynI[yi][2 * w]     = __float2int_rn(s0 * SCALE);
            ynI[yi][2 * w + 1] = __float2int_rn(s1 * SCALE);
        }
    };
    // scan tile (local index sp): slds[sp&1], ynI[sp%3]; exact top-16 + zero
    auto scan = [&](int sp) {
        const int n0p = (b + sp * NBLK) * 16;
        const int r = lane;
        volatile int* sb = &slds[sp & 1][0][0];
        volatile int* yb = &ynI[sp % 3][0];
        int thr = thrS[r], thrn = thrnS[r], cnt = cntS[r];
        for (int j = 0; j < 16; j++) {
            const int n = n0p + j;
            if (n >= N) break;
            const int s = yb[j] - 2 * sb[j * 65 + r];
            if (lexLessI(s, n, thr, thrn)) {
                if (cnt < 16) {
                    topdI[cnt][r] = s; topiI[cnt][r] = n; cnt++;
                    if (cnt == 16) {
                        int tv = topdI[0][r], tn = topiI[0][r];
                        #pragma unroll
                        for (int u = 1; u < 16; u++) {
                            int v = topdI[u][r], nn = topiI[u][r];
                            if (!lexLessI(v, nn, tv, tn)) { tv = v; tn = nn; }
                        }
                        thr = tv; thrn = tn;
                    }
                } else {
                    #pragma unroll
                    for (int u = 0; u < 16; u++)
                        if (topdI[u][r] == thr && topiI[u][r] == thrn) {
                            topdI[u][r] = s; topiI[u][r] = n; break;
                        }
                    int tv = topdI[0][r], tn = topiI[0][r];
                    #pragma unroll
                    for (int u = 1; u < 16; u++) {
                        int v = topdI[u][r], nn = topiI[u][r];
                        if (!lexLessI(v, nn, tv, tn)) { tv = v; tn = nn; }
                    }
                    thr = tv; thrn = tn;
                }
            }
        }
        thrS[r] = thr; thrnS[r] = thrn; cntS[r] = cnt;
        for (int e2 = lane; e2 < 16 * 65; e2 += 64) sb[e2] = 0;
    };

    // ---- prologue: fully stage tile b (sc=0) into ybuf[0], ynI[0] ----
    issue(b);
    cvt_write(0, 0);
    __syncthreads();

    int sc = 0;
    for (int t = b; t < TT; t += NBLK, ++sc) {
        const int tb = sc & 1;
        const bool haveNext = (t + NBLK) < TT;

        // (1) issue next tile's loads early (stay in flight through compute)
        if (haveNext) issue(t + NBLK);
        __builtin_amdgcn_sched_barrier(0);

        // (2) compute current tile from ybuf[tb]
        f32x4 acc0 = {0.f,0.f,0.f,0.f}, acc1 = {0.f,0.f,0.f,0.f};
        f32x4 acc2 = {0.f,0.f,0.f,0.f}, acc3 = {0.f,0.f,0.f,0.f};
        #pragma unroll
        for (int ks2 = 0; ks2 < 2; ks2++) {
            const f16x8 bf = *(const f16x8*)(ybuf[tb] + li * YROWB
                                             + 128 * w + 64 * ks2 + 16 * q);
            acc0 = __builtin_amdgcn_mfma_f32_16x16x32_f16(__builtin_bit_cast(f16x8, a[ks2][0]), bf, acc0, 0, 0, 0);
            acc1 = __builtin_amdgcn_mfma_f32_16x16x32_f16(__builtin_bit_cast(f16x8, a[ks2][1]), bf, acc1, 0, 0, 0);
            acc2 = __builtin_amdgcn_mfma_f32_16x16x32_f16(__builtin_bit_cast(f16x8, a[ks2][2]), bf, acc2, 0, 0, 0);
            acc3 = __builtin_amdgcn_mfma_f32_16x16x32_f16(__builtin_bit_cast(f16x8, a[ks2][3]), bf, acc3, 0, 0, 0);
        }
        // (3) fold into slds[tb] (exact int, order-free)
        #pragma unroll
        for (int jj = 0; jj < 4; jj++) {
            atomicAdd(&slds[tb][li][ 0 + 4 * q + jj], __float2int_rn(acc0[jj] * SCALE));
            atomicAdd(&slds[tb][li][16 + 4 * q + jj], __float2int_rn(acc1[jj] * SCALE));
            atomicAdd(&slds[tb][li][32 + 4 * q + jj], __float2int_rn(acc2[jj] * SCALE));
            atomicAdd(&slds[tb][li][48 + 4 * q + jj], __float2int_rn(acc3[jj] * SCALE));
        }
        // (4) scan previous tile (overlapped; distinct slds AND ynI buffers)
        if (sc > 0 && w == ((sc - 1) & 7)) scan(sc - 1);
        // (5) cvt + write next tile: ybuf[tb^1], ynI[(sc+1)%3]
        if (haveNext) cvt_write(tb ^ 1, (sc + 1) % 3);
        // (6) one barrier per tile; vmcnt NOT drained (raw s_barrier)
        asm volatile("s_waitcnt lgkmcnt(0)");
        __builtin_amdgcn_sched_barrier(0);
        __builtin_amdgcn_s_barrier();
        __builtin_amdgcn_sched_barrier(0);
    }

    // epilogue: scan the last tile
    if (w == ((myCnt - 1) & 7)) scan(myCnt - 1);
    __syncthreads();

    if (tid < 64) {
        const int c = cntS[tid];
        const size_t base = ((size_t)b * 64 + tid) * 16;
        for (int j = 0; j < 16; j++) {
            cs[base + j] = (j < c) ? ((float)topdI[j][tid] * (1.0f / SCALE)) : INF_F;
            ci[base + j] = (j < c) ? topiI[j][tid] : INF_I;
        }
    }
}

// ---------------------------------------------------------------------------
// Kernel 2: per batch row — approx global top-24 merge (replace-max),
// fp64 exact recompute (4 parallel chains), exact sort -> top-16, softmax,
// action gather, outputs.
// ---------------------------------------------------------------------------
__global__ __launch_bounds__(256) void merge_kernel(
    const float* __restrict__ cs, const int* __restrict__ ci,
    const float* __restrict__ brep, const float* __restrict__ reps,
    const float* __restrict__ acts,
    float* __restrict__ out, int NLISTS, int N, int BA)
{
    const int r = blockIdx.x;
    const int tid = threadIdx.x;
    __shared__ __align__(16) float xrow[512];
    __shared__ float S1s[256 * KM];
    __shared__ int   S1i[256 * KM];
    __shared__ float S2s[32 * KM];
    __shared__ int   S2i[32 * KM];
    __shared__ double fd[KM];
    __shared__ int    fn[KM];

    if (tid < 128)
        *(float4*)(&xrow[tid * 4]) = *(const float4*)(&brep[(size_t)r * 512 + tid * 4]);

    float ls[KM]; int li[KM];
    #pragma unroll
    for (int j = 0; j < KM; j++) { ls[j] = INF_F; li[j] = INF_I; }
    float mv = INF_F; int mn = INF_I; int mp = 0;
    const int total = NLISTS * 16;
    for (int e = tid; e < total; e += 256) {
        const int blk = e >> 4, j = e & 15;
        const size_t a = (size_t)blk * 1024 + (size_t)r * 16 + j;
        const float s = cs[a]; const int n = ci[a];
        if (lexLess(s, n, mv, mn)) {
            ls[mp] = s; li[mp] = n;
            mv = ls[0]; mn = li[0]; mp = 0;
            #pragma unroll
            for (int u = 1; u < KM; u++)
                if (!lexLess(ls[u], li[u], mv, mn)) { mv = ls[u]; mn = li[u]; mp = u; }
        }
    }
    #pragma unroll
    for (int j = 0; j < KM; j++) { S1s[tid * KM + j] = ls[j]; S1i[tid * KM + j] = li[j]; }
    __syncthreads();

    if (tid < 32) {
        #pragma unroll
        for (int j = 0; j < KM; j++) { ls[j] = INF_F; li[j] = INF_I; }
        mv = INF_F; mn = INF_I; mp = 0;
        for (int e = tid * 8 * KM; e < (tid * 8 + 8) * KM; e++) {
            const float s = S1s[e]; const int n = S1i[e];
            if (lexLess(s, n, mv, mn)) {
                ls[mp] = s; li[mp] = n;
                mv = ls[0]; mn = li[0]; mp = 0;
                #pragma unroll
                for (int u = 1; u < KM; u++)
                    if (!lexLess(ls[u], li[u], mv, mn)) { mv = ls[u]; mn = li[u]; mp = u; }
            }
        }
        #pragma unroll
        for (int j = 0; j < KM; j++) { S2s[tid * KM + j] = ls[j]; S2i[tid * KM + j] = li[j]; }
    }
    __syncthreads();

    if (tid == 0) {
        #pragma unroll
        for (int j = 0; j < KM; j++) { ls[j] = INF_F; li[j] = INF_I; }
        mv = INF_F; mn = INF_I; mp = 0;
        for (int e = 0; e < 32 * KM; e++) {
            const float s = S2s[e]; const int n = S2i[e];
            if (lexLess(s, n, mv, mn)) {
                ls[mp] = s; li[mp] = n;
                mv = ls[0]; mn = li[0]; mp = 0;
                #pragma unroll
                for (int u = 1; u < KM; u++)
                    if (!lexLess(ls[u], li[u], mv, mn)) { mv = ls[u]; mn = li[u]; mp = u; }
            }
        }
        for (int j = 0; j < KM; j++) fn[j] = li[j];
    }
    __syncthreads();

    if (tid < KM) {
        const int n = fn[tid];
        double d = 1.0e300;
        if (n >= 0 && n < N) {
            double d0a = 0.0, d1a = 0.0, d2a = 0.0, d3a = 0.0;
            const float* yp = reps + (size_t)n * 512;
            for (int i = 0; i < 512; i += 4) {
                float4 yv = *(const float4*)(yp + i);
                double e0 = (double)xrow[i + 0] - (double)yv.x;
                double e1 = (double)xrow[i + 1] - (double)yv.y;
                double e2 = (double)xrow[i + 2] - (double)yv.z;
                double e3 = (double)xrow[i + 3] - (double)yv.w;
                d0a += e0 * e0; d1a += e1 * e1; d2a += e2 * e2; d3a += e3 * e3;
            }
            d = (d0a + d1a) + (d2a + d3a);
        }
        fd[tid] = d;
    }
    __syncthreads();

    if (tid == 0) {
        int ord[KM];
        for (int j = 0; j < KM; j++) ord[j] = j;
        for (int a = 0; a < 16; a++) {
            int best = a;
            for (int u = a + 1; u < KM; u++) {
                const int ou = ord[u], ob = ord[best];
                if (fd[ou] < fd[ob] || (fd[ou] == fd[ob] && fn[ou] < fn[ob])) best = u;
            }
            int tmp = ord[a]; ord[a] = ord[best]; ord[best] = tmp;
        }
        double dist[16];
        for (int j = 0; j < 16; j++) {
            double v = fd[ord[j]];
            dist[j] = sqrt(v > 0.0 ? v : 0.0);
        }
        double wv[16], wsum = 0.0;
        for (int j = 0; j < 16; j++) { wv[j] = exp(dist[0] - dist[j]); wsum += wv[j]; }
        for (int a = 0; a < 7; a++) {
            double s = 0.0;
            for (int j = 0; j < 16; j++)
                s += wv[j] * (double)acts[(size_t)fn[ord[j]] * 7 + a];
            out[r * 7 + a] = (float)(s / wsum);
        }
        for (int j = 0; j < 16; j++)
            out[BA + r * 16 + j] = (float)fn[ord[j]];
    }
}

extern "C" void kernel_launch(void* const* d_in, const int* in_sizes, int n_in,
                              void* d_out, int out_size, void* d_ws, size_t ws_size,
                              hipStream_t stream) {
    const float* brep = (const float*)d_in[0];
    const float* reps = (const float*)d_in[1];
    const float* acts = (const float*)d_in[2];
    const int D = 512;
    const int B = in_sizes[0] / D;   // 64
    const int N = in_sizes[1] / D;   // 500000
    float* out = (float*)d_out;

    // 512 blocks of 512 threads = 2 blocks/CU (51 KB LDS, 16 waves/CU).
    int NBLK = 512;
    const size_t perblk = (size_t)64 * 16 * 8;        // cs+ci bytes per block
    while (NBLK > 1 && (size_t)NBLK * perblk > ws_size) NBLK >>= 1;

    float* cs = (float*)d_ws;
    int* ci = (int*)((char*)d_ws + (size_t)NBLK * 64 * 16 * 4);

    const int TT = (N + 15) / 16;                     // 16-row tiles

    dist_topk_kernel<<<NBLK, 512, 0, stream>>>(reps, brep, cs, ci, N, TT, NBLK);
    merge_kernel<<<B, 256, 0, stream>>>(cs, ci, brep, reps, acts, out, NBLK, N, B * 7);
}

// Round 14
// 1429.419 us; speedup vs baseline: 1.1194x; 1.1194x over previous
//
#include <hip/hip_runtime.h>
#include <stdint.h>

typedef _Float16 f16;
typedef _Float16 f16x8 __attribute__((ext_vector_type(8)));
typedef float f32x4 __attribute__((ext_vector_type(4)));

#define INF_F __builtin_inff()
#define INF_I 0x7fffffff
#define KM 24            // merge candidate margin
#define SCALE 262144.0f  // 2^18 fixed-point scale

__device__ __forceinline__ bool lexLess(float s1, int n1, float s2, int n2) {
    return (s1 < s2) || (s1 == s2 && n1 < n2);
}
__device__ __forceinline__ bool lexLessI(int s1, int n1, int s2, int n2) {
    return (s1 < s2) || (s1 == s2 && n1 < n2);
}

__device__ __forceinline__ uint4 pack8(const float4 a, const float4 b) {
    const auto p0 = __builtin_amdgcn_cvt_pkrtz(a.x, a.y);
    const auto p1 = __builtin_amdgcn_cvt_pkrtz(a.z, a.w);
    const auto p2 = __builtin_amdgcn_cvt_pkrtz(b.x, b.y);
    const auto p3 = __builtin_amdgcn_cvt_pkrtz(b.z, b.w);
    uint4 u;
    u.x = __builtin_bit_cast(unsigned, p0);
    u.y = __builtin_bit_cast(unsigned, p1);
    u.z = __builtin_bit_cast(unsigned, p2);
    u.w = __builtin_bit_cast(unsigned, p3);
    return u;
}
__device__ __forceinline__ float s4(const float4 v) {
    return (v.x + v.y) + (v.z + v.w);
}

// ---------------------------------------------------------------------------
// ABLATION: deep-burst stream read. 1024 blocks x 8 waves, <=64 VGPR ->
// 32 waves/CU. Per iter each wave issues 8x dwordx4 (8 KB sequential),
// consumes all, drains, repeats. ~256 KB outstanding per CU. Reads reps
// exactly once; sinks sums to ws (never validated). Answers: does deep
// per-wave burst + max occupancy break the ~0.9 TB/s wall?
// ---------------------------------------------------------------------------
__global__ __launch_bounds__(512, 8) void abl_deep(
    const float* __restrict__ reps, float* __restrict__ sink,
    int iters, long limitB)
{
    const int gw = blockIdx.x * 8 + (threadIdx.x >> 6);
    const int lane = threadIdx.x & 63;
    const char* base = (const char*)reps;
    float acc = 0.f;
    for (int it = 0; it < iters; ++it) {
        const long off = ((long)gw * iters + it) * 8192;
        if (off + 8192 > limitB) break;
        const char* p = base + off + lane * 16;
        const float4 v0 = *(const float4*)(p);
        const float4 v1 = *(const float4*)(p + 1024);
        const float4 v2 = *(const float4*)(p + 2048);
        const float4 v3 = *(const float4*)(p + 3072);
        const float4 v4 = *(const float4*)(p + 4096);
        const float4 v5 = *(const float4*)(p + 5120);
        const float4 v6 = *(const float4*)(p + 6144);
        const float4 v7 = *(const float4*)(p + 7168);
        acc += ((s4(v0) + s4(v1)) + (s4(v2) + s4(v3)))
             + ((s4(v4) + s4(v5)) + (s4(v6) + s4(v7)));
        asm volatile("s_waitcnt vmcnt(0)" ::: "memory");
        __builtin_amdgcn_sched_barrier(0);
    }
    #pragma unroll
    for (int d = 1; d < 64; d <<= 1) acc += __shfl_xor(acc, d);
    if (lane == 0) atomicAdd(&sink[blockIdx.x], acc);
}

// ---------------------------------------------------------------------------
// Kernel 1 (PRODUCTION, R10 verbatim — best known: dist 854 us, passed):
// k-split streaming scores + per-block top-16 per batch row.
// ---------------------------------------------------------------------------
__global__ __launch_bounds__(256, 4) void dist_topk_kernel(
    const float* __restrict__ reps, const float* __restrict__ brep,
    float* __restrict__ cs, int* __restrict__ ci,
    int N, int TT, int NBLK)
{
    __shared__ int slds[64][65];                  // [rep-row][64 dots + ynorm]
    __shared__ int topdI[16][64];
    __shared__ int topiI[16][64];
    __shared__ int thrS[64], thrnS[64], cntS[64];

    const int tid = threadIdx.x;
    const int w = tid >> 6, lane = tid & 63;
    const int li = lane & 15, q = lane >> 4;
    const int b = blockIdx.x;

    uint4 a[4][4];
    #pragma unroll
    for (int ks = 0; ks < 4; ks++)
        #pragma unroll
        for (int mt = 0; mt < 4; mt++) {
            const float* src = brep + (mt * 16 + li) * 512 + 128 * w + 32 * ks + 8 * q;
            const float4 x0 = *(const float4*)(src);
            const float4 x1 = *(const float4*)(src + 4);
            a[ks][mt] = pack8(x0, x1);
        }

    if (tid < 64) { thrS[tid] = INF_I; thrnS[tid] = INF_I; cntS[tid] = 0; }
    for (int i = tid; i < 64 * 65; i += 256) ((int*)slds)[i] = 0;
    __syncthreads();

    int sc = 0;
    for (int t = b; t < TT; t += NBLK, sc++) {
        const int n0 = t * 64;

        #pragma unroll 1
        for (int nsub = 0; nsub < 4; nsub++) {
            const int rowl = n0 + nsub * 16 + li;
            const size_t rowc = (size_t)(rowl < N ? rowl : N - 1);
            const float* bp = reps + rowc * 512 + 128 * w + 8 * q;

            f32x4 acc0 = {0.f,0.f,0.f,0.f}, acc1 = {0.f,0.f,0.f,0.f};
            f32x4 acc2 = {0.f,0.f,0.f,0.f}, acc3 = {0.f,0.f,0.f,0.f};
            float yn = 0.f;

            float4 y0A = *(const float4*)(bp);
            float4 y1A = *(const float4*)(bp + 4);
            #pragma unroll
            for (int ks = 0; ks < 4; ks++) {
                float4 y0B, y1B;
                if (ks < 3) {
                    y0B = *(const float4*)(bp + (ks + 1) * 32);
                    y1B = *(const float4*)(bp + (ks + 1) * 32 + 4);
                }
                yn = fmaf(y0A.x, y0A.x, fmaf(y0A.y, y0A.y, fmaf(y0A.z, y0A.z, fmaf(y0A.w, y0A.w, yn))));
                yn = fmaf(y1A.x, y1A.x, fmaf(y1A.y, y1A.y, fmaf(y1A.z, y1A.z, fmaf(y1A.w, y1A.w, yn))));
                const f16x8 bf = __builtin_bit_cast(f16x8, pack8(y0A, y1A));
                acc0 = __builtin_amdgcn_mfma_f32_16x16x32_f16(__builtin_bit_cast(f16x8, a[ks][0]), bf, acc0, 0, 0, 0);
                acc1 = __builtin_amdgcn_mfma_f32_16x16x32_f16(__builtin_bit_cast(f16x8, a[ks][1]), bf, acc1, 0, 0, 0);
                acc2 = __builtin_amdgcn_mfma_f32_16x16x32_f16(__builtin_bit_cast(f16x8, a[ks][2]), bf, acc2, 0, 0, 0);
                acc3 = __builtin_amdgcn_mfma_f32_16x16x32_f16(__builtin_bit_cast(f16x8, a[ks][3]), bf, acc3, 0, 0, 0);
                if (ks < 3) { y0A = y0B; y1A = y1B; }
            }

            float ys = yn;
            ys += __shfl_xor(ys, 16);
            ys += __shfl_xor(ys, 32);
            const int nloc = nsub * 16 + li;
            if (q == 0) atomicAdd(&slds[nloc][64], __float2int_rn(ys * SCALE));
            #pragma unroll
            for (int jj = 0; jj < 4; jj++) {
                atomicAdd(&slds[nloc][ 0 + 4 * q + jj], __float2int_rn(acc0[jj] * SCALE));
                atomicAdd(&slds[nloc][16 + 4 * q + jj], __float2int_rn(acc1[jj] * SCALE));
                atomicAdd(&slds[nloc][32 + 4 * q + jj], __float2int_rn(acc2[jj] * SCALE));
                atomicAdd(&slds[nloc][48 + 4 * q + jj], __float2int_rn(acc3[jj] * SCALE));
            }
        }

        __syncthreads();   // all atomics of this tile done

        if (w == (sc & 3)) {
            const int r = lane;
            const int* sb = &slds[0][0];
            int thr = thrS[r], thrn = thrnS[r], cnt = cntS[r];
            for (int j = 0; j < 64; j++) {
                const int n = n0 + j;
                if (n >= N) break;
                const int s = sb[j * 65 + 64] - 2 * sb[j * 65 + r];
                if (lexLessI(s, n, thr, thrn)) {
                    if (cnt < 16) {
                        topdI[cnt][r] = s; topiI[cnt][r] = n; cnt++;
                        if (cnt == 16) {
                            int tv = topdI[0][r], tn = topiI[0][r];
                            #pragma unroll
                            for (int u = 1; u < 16; u++) {
                                int v = topdI[u][r], nn = topiI[u][r];
                                if (!lexLessI(v, nn, tv, tn)) { tv = v; tn = nn; }
                            }
                            thr = tv; thrn = tn;
                        }
                    } else {
                        #pragma unroll
                        for (int u = 0; u < 16; u++)
                            if (topdI[u][r] == thr && topiI[u][r] == thrn) {
                                topdI[u][r] = s; topiI[u][r] = n; break;
                            }
                        int tv = topdI[0][r], tn = topiI[0][r];
                        #pragma unroll
                        for (int u = 1; u < 16; u++) {
                            int v = topdI[u][r], nn = topiI[u][r];
                            if (!lexLessI(v, nn, tv, tn)) { tv = v; tn = nn; }
                        }
                        thr = tv; thrn = tn;
                    }
                }
            }
            thrS[r] = thr; thrnS[r] = thrn; cntS[r] = cnt;
            for (int e2 = lane; e2 < 64 * 65; e2 += 64) (&slds[0][0])[e2] = 0;
        }

        __syncthreads();   // slds zeroed before next tile's atomics
    }

    __syncthreads();
    if (tid < 64) {
        const int c = cntS[tid];
        const size_t base = ((size_t)b * 64 + tid) * 16;
        for (int j = 0; j < 16; j++) {
            cs[base + j] = (j < c) ? ((float)topdI[j][tid] * (1.0f / SCALE)) : INF_F;
            ci[base + j] = (j < c) ? topiI[j][tid] : INF_I;
        }
    }
}

// ---------------------------------------------------------------------------
// Kernel 2 (R10 verbatim): approx global top-24 merge, fp64 exact recompute,
// exact sort -> top-16, softmax weights, action gather, outputs.
// ---------------------------------------------------------------------------
__global__ __launch_bounds__(256) void merge_kernel(
    const float* __restrict__ cs, const int* __restrict__ ci,
    const float* __restrict__ brep, const float* __restrict__ reps,
    const float* __restrict__ acts,
    float* __restrict__ out, int NLISTS, int N, int BA)
{
    const int r = blockIdx.x;
    const int tid = threadIdx.x;
    __shared__ __align__(16) float xrow[512];
    __shared__ float S1s[256 * KM];
    __shared__ int   S1i[256 * KM];
    __shared__ float S2s[32 * KM];
    __shared__ int   S2i[32 * KM];
    __shared__ double fd[KM];
    __shared__ int    fn[KM];

    if (tid < 128)
        *(float4*)(&xrow[tid * 4]) = *(const float4*)(&brep[(size_t)r * 512 + tid * 4]);

    float ls[KM]; int li[KM];
    #pragma unroll
    for (int j = 0; j < KM; j++) { ls[j] = INF_F; li[j] = INF_I; }
    float mv = INF_F; int mn = INF_I; int mp = 0;
    const int total = NLISTS * 16;
    for (int e = tid; e < total; e += 256) {
        const int blk = e >> 4, j = e & 15;
        const size_t a = (size_t)blk * 1024 + (size_t)r * 16 + j;
        const float s = cs[a]; const int n = ci[a];
        if (lexLess(s, n, mv, mn)) {
            ls[mp] = s; li[mp] = n;
            mv = ls[0]; mn = li[0]; mp = 0;
            #pragma unroll
            for (int u = 1; u < KM; u++)
                if (!lexLess(ls[u], li[u], mv, mn)) { mv = ls[u]; mn = li[u]; mp = u; }
        }
    }
    #pragma unroll
    for (int j = 0; j < KM; j++) { S1s[tid * KM + j] = ls[j]; S1i[tid * KM + j] = li[j]; }
    __syncthreads();

    if (tid < 32) {
        #pragma unroll
        for (int j = 0; j < KM; j++) { ls[j] = INF_F; li[j] = INF_I; }
        mv = INF_F; mn = INF_I; mp = 0;
        for (int e = tid * 8 * KM; e < (tid * 8 + 8) * KM; e++) {
            const float s = S1s[e]; const int n = S1i[e];
            if (lexLess(s, n, mv, mn)) {
                ls[mp] = s; li[mp] = n;
                mv = ls[0]; mn = li[0]; mp = 0;
                #pragma unroll
                for (int u = 1; u < KM; u++)
                    if (!lexLess(ls[u], li[u], mv, mn)) { mv = ls[u]; mn = li[u]; mp = u; }
            }
        }
        #pragma unroll
        for (int j = 0; j < KM; j++) { S2s[tid * KM + j] = ls[j]; S2i[tid * KM + j] = li[j]; }
    }
    __syncthreads();

    if (tid == 0) {
        #pragma unroll
        for (int j = 0; j < KM; j++) { ls[j] = INF_F; li[j] = INF_I; }
        mv = INF_F; mn = INF_I; mp = 0;
        for (int e = 0; e < 32 * KM; e++) {
            const float s = S2s[e]; const int n = S2i[e];
            if (lexLess(s, n, mv, mn)) {
                ls[mp] = s; li[mp] = n;
                mv = ls[0]; mn = li[0]; mp = 0;
                #pragma unroll
                for (int u = 1; u < KM; u++)
                    if (!lexLess(ls[u], li[u], mv, mn)) { mv = ls[u]; mn = li[u]; mp = u; }
            }
        }
        for (int j = 0; j < KM; j++) fn[j] = li[j];
    }
    __syncthreads();

    if (tid < KM) {
        const int n = fn[tid];
        double d = 1.0e300;
        if (n >= 0 && n < N) {
            double d0a = 0.0, d1a = 0.0, d2a = 0.0, d3a = 0.0;
            const float* yp = reps + (size_t)n * 512;
            for (int i = 0; i < 512; i += 4) {
                float4 yv = *(const float4*)(yp + i);
                double e0 = (double)xrow[i + 0] - (double)yv.x;
                double e1 = (double)xrow[i + 1] - (double)yv.y;
                double e2 = (double)xrow[i + 2] - (double)yv.z;
                double e3 = (double)xrow[i + 3] - (double)yv.w;
                d0a += e0 * e0; d1a += e1 * e1; d2a += e2 * e2; d3a += e3 * e3;
            }
            d = (d0a + d1a) + (d2a + d3a);
        }
        fd[tid] = d;
    }
    __syncthreads();

    if (tid == 0) {
        int ord[KM];
        for (int j = 0; j < KM; j++) ord[j] = j;
        for (int a = 0; a < 16; a++) {
            int best = a;
            for (int u = a + 1; u < KM; u++) {
                const int ou = ord[u], ob = ord[best];
                if (fd[ou] < fd[ob] || (fd[ou] == fd[ob] && fn[ou] < fn[ob])) best = u;
            }
            int tmp = ord[a]; ord[a] = ord[best]; ord[best] = tmp;
        }
        double dist[16];
        for (int j = 0; j < 16; j++) {
            double v = fd[ord[j]];
            dist[j] = sqrt(v > 0.0 ? v : 0.0);
        }
        double wv[16], wsum = 0.0;
        for (int j = 0; j < 16; j++) { wv[j] = exp(dist[0] - dist[j]); wsum += wv[j]; }
        for (int a = 0; a < 7; a++) {
            double s = 0.0;
            for (int j = 0; j < 16; j++)
                s += wv[j] * (double)acts[(size_t)fn[ord[j]] * 7 + a];
            out[r * 7 + a] = (float)(s / wsum);
        }
        for (int j = 0; j < 16; j++)
            out[BA + r * 16 + j] = (float)fn[ord[j]];
    }
}

extern "C" void kernel_launch(void* const* d_in, const int* in_sizes, int n_in,
                              void* d_out, int out_size, void* d_ws, size_t ws_size,
                              hipStream_t stream) {
    const float* brep = (const float*)d_in[0];
    const float* reps = (const float*)d_in[1];
    const float* acts = (const float*)d_in[2];
    const int D = 512;
    const int B = in_sizes[0] / D;   // 64
    const int N = in_sizes[1] / D;   // 500000
    float* out = (float*)d_out;

    int NBLK = 1024;
    const size_t perblk = (size_t)64 * 16 * 8;        // cs+ci bytes per block
    while (NBLK > 1 && (size_t)NBLK * perblk + 8192 > ws_size) NBLK >>= 1;

    float* cs = (float*)d_ws;
    int* ci = (int*)((char*)d_ws + (size_t)NBLK * 64 * 16 * 4);
    float* sink = (float*)((char*)d_ws + (size_t)NBLK * perblk);

    const int TT = (N + 63) / 64;                     // 64-row tiles

    // ---- ablation dispatch: deep-burst stream probe (see theory) ----
    const long limitB = (long)N * (D * 4);
    const int iters = (int)(limitB / ((long)8192 * 8192));   // ~15
    abl_deep<<<1024, 512, 0, stream>>>(reps, sink, iters, limitB);

    // ---- production pipeline (R10 verbatim) ----
    dist_topk_kernel<<<NBLK, 256, 0, stream>>>(reps, brep, cs, ci, N, TT, NBLK);
    merge_kernel<<<B, 256, 0, stream>>>(cs, ci, brep, reps, acts, out, NBLK, N, B * 7);
}